// Round 6
// baseline (610.996 us; speedup 1.0000x reference)
//
#include <hip/hip_runtime.h>

typedef short   short8  __attribute__((ext_vector_type(8)));
typedef unsigned short ushort8 __attribute__((ext_vector_type(8)));
typedef unsigned short bf4     __attribute__((ext_vector_type(4)));
typedef float   floatx4 __attribute__((ext_vector_type(4)));

__device__ __forceinline__ float bf2f(unsigned short h) {
    unsigned int u = ((unsigned int)h) << 16;
    return __builtin_bit_cast(float, u);
}
__device__ __forceinline__ unsigned short f2bf(float f) {
    unsigned int u = __builtin_bit_cast(unsigned int, f);
    u += 0x7fffu + ((u >> 16) & 1u);   // round-to-nearest-even
    return (unsigned short)(u >> 16);
}

// ---------------- fused dtype detection + deg zeroing ----------------
// flags[0] != 0  =>  float tensors delivered as fp32 (else bf16)
// flags[1] != 0  =>  edge_index delivered as int32 (else int64)

__global__ __launch_bounds__(256) void k_detect(const unsigned short* __restrict__ X,
                                                int nPairs, const int* __restrict__ ei,
                                                int E, int n,
                                                int* __restrict__ flags,
                                                int* __restrict__ deg) {
    int i = blockIdx.x * 256 + threadIdx.x;
    if (i < nPairs) {
        unsigned short w = X[2 * i];
        if ((w & 0x7F80u) == 0x7F80u) atomicOr(&flags[0], 1);
    }
    if (i < E) {
        if (ei[2 * i + 1] != 0) atomicOr(&flags[1], 1);
    }
    if (i < n) deg[i] = 0;
}

// ---------------- fused bias converts (4 segments -> one fp32 buffer) --------

__global__ __launch_bounds__(256) void k_cvtb(const void* __restrict__ b1,
                                              const void* __restrict__ b2,
                                              const void* __restrict__ b3,
                                              const void* __restrict__ b4,
                                              float* __restrict__ out,
                                              int L1, int L2, int L3, int L4,
                                              const int* __restrict__ flags) {
    int i = blockIdx.x * 256 + threadIdx.x;
    int n = L1 + L2 + L3 + L4;
    if (i >= n) return;
    const void* src; int off;
    if (i < L1)                { src = b1; off = i; }
    else if (i < L1 + L2)      { src = b2; off = i - L1; }
    else if (i < L1 + L2 + L3) { src = b3; off = i - L1 - L2; }
    else                       { src = b4; off = i - L1 - L2 - L3; }
    out[i] = flags[0] ? ((const float*)src)[off]
                      : bf2f(((const unsigned short*)src)[off]);
}

// ---------------- LDS-tiled transpose-convert: out[c][r] = bf16(in[r][c]) ----
// old k_tcvt did fully-scattered 2B stores; 32x32 tile makes both sides coalesced.

__global__ __launch_bounds__(256) void k_tcvt(const void* __restrict__ in,
                                              unsigned short* __restrict__ out,
                                              int R, int C, const int* __restrict__ flags) {
    __shared__ unsigned short tl[32][40];
    const int c0 = blockIdx.x * 32, r0 = blockIdx.y * 32;
    const int tx = threadIdx.x & 31, ty = threadIdx.x >> 5;   // 32x8
    const bool f32 = flags[0] != 0;
#pragma unroll
    for (int k = 0; k < 32; k += 8) {
        int r = r0 + ty + k, c = c0 + tx;
        unsigned short v = 0;
        if (r < R && c < C)
            v = f32 ? f2bf(((const float*)in)[(long)r * C + c])
                    : ((const unsigned short*)in)[(long)r * C + c];
        tl[ty + k][tx] = v;
    }
    __syncthreads();
#pragma unroll
    for (int k = 0; k < 32; k += 8) {
        int c = c0 + ty + k, r = r0 + tx;
        if (c < C && r < R) out[(long)c * R + r] = tl[tx][ty + k];
    }
}

// ---------------- graph setup ----------------

__global__ __launch_bounds__(256) void k_count(const int* __restrict__ ei, int E, int n,
                                               const int* __restrict__ flags,
                                               int* __restrict__ deg) {
    int e = blockIdx.x * 256 + threadIdx.x;
    if (e >= E) return;
    int sh = (flags[1] == 0) ? 1 : 0;           // int64 -> stride-2 words
    int d = ei[(long)(E + e) << sh];
    if ((unsigned)d < (unsigned)n) atomicAdd(&deg[d], 1);
}

__global__ __launch_bounds__(256) void k_dinv(const int* __restrict__ deg,
                                              float* __restrict__ dinv, int n) {
    int i = blockIdx.x * 256 + threadIdx.x;
    if (i < n) dinv[i] = rsqrtf((float)(deg[i] + 1));  // +1 self-loop
}

__global__ __launch_bounds__(1024) void k_scan(const int* __restrict__ deg,
                                               int* __restrict__ row_start,
                                               int* __restrict__ cursor, int n) {
    __shared__ int sums[1024];
    int t = threadIdx.x;
    int CH = (n + 1 + 1023) / 1024;
    int base = t * CH;
    int s = 0;
    for (int i = 0; i < CH; i++) {
        int idx = base + i;
        if (idx < n) s += deg[idx];
    }
    sums[t] = s;
    __syncthreads();
    for (int off = 1; off < 1024; off <<= 1) {
        int v = (t >= off) ? sums[t - off] : 0;
        __syncthreads();
        if (t >= off) sums[t] += v;
        __syncthreads();
    }
    int run = (t > 0) ? sums[t - 1] : 0;
    for (int i = 0; i < CH; i++) {
        int idx = base + i;
        if (idx < n) {
            row_start[idx] = run;
            cursor[idx] = run;
            run += deg[idx];
        } else if (idx == n) {
            row_start[n] = run;
        }
    }
}

__global__ __launch_bounds__(256) void k_fill(const int* __restrict__ ei, int E, int n,
                                              const int* __restrict__ flags,
                                              int* __restrict__ cursor,
                                              int* __restrict__ csr) {
    int e = blockIdx.x * 256 + threadIdx.x;
    if (e >= E) return;
    int sh = (flags[1] == 0) ? 1 : 0;
    int s = ei[(long)e << sh];
    int d = ei[(long)(E + e) << sh];
    if ((unsigned)d >= (unsigned)n || (unsigned)s >= (unsigned)n) return;
    int p = atomicAdd(&cursor[d], 1);
    csr[p] = s;
}

// ---------------- NT GEMM: C[M,N] = A[M,K] * Bt[N,K]^T (+bias), fp32 acc ------
// A/Bt bf16 OR fp32 (runtime per-operand flag; wave-uniform branch, VECTOR
// float4 loads -- round-2's regression was scalar fp32 loads, not conversion
// per se). Conversion happens after the MFMA phase, in the load shadow.
// Round-5 structure kept: LDS double-buffer, one barrier/K-step, swapped-
// operand MFMA (row-major vector epilogue stores).
// NOTE (round-1): all acc/frag loops MUST be #pragma unroll'd (rule #20).

__device__ __forceinline__ void ld_any(const void* base, long elem, bool f32,
                                       ushort8& u, floatx4& f0, floatx4& f1) {
    if (f32) {
        const floatx4* p = (const floatx4*)((const float*)base + elem);
        f0 = p[0]; f1 = p[1];
    } else {
        u = *(const ushort8*)((const unsigned short*)base + elem);
    }
}
__device__ __forceinline__ ushort8 cv_any(bool f32, ushort8 u, floatx4 f0, floatx4 f1) {
    if (!f32) return u;
    ushort8 r;
#pragma unroll
    for (int j = 0; j < 4; j++) { r[j] = f2bf(f0[j]); r[4 + j] = f2bf(f1[j]); }
    return r;
}

template <int BM, int BN>
__global__ __launch_bounds__(256, (BN == 128 ? 3 : 4))
void gemm_nt(const void* __restrict__ A, int aMaybeF32,
             const void* __restrict__ Bt, int bMaybeF32,
             void* __restrict__ Cv, long coff,
             void* __restrict__ Cv2, long c2off,
             const float* __restrict__ bias,
             int M, int N, int K, int finalOut,
             const int* __restrict__ flags) {
    constexpr int BK = 32, LDT = 40;   // pad 32->40: only free 2-way conflicts
    constexpr int JR = BN / 16;        // B fragments per wave
    constexpr int SM = BM / 64;        // A subtiles per wave (1 or 2)
    __shared__ unsigned short sA[2][BM * LDT];
    __shared__ unsigned short sB[2][BN * LDT];
    const bool isf32 = flags[0] != 0;
    const bool af32 = aMaybeF32 && isf32;
    const bool bf32 = bMaybeF32 && isf32;
    const bool of32 = finalOut && isf32;
    const bool hasb = bias != nullptr;
    const int t = threadIdx.x;

    // bijective XCD-aware swizzle (contiguous chunk per XCD)
    const int GX = gridDim.x;
    const int nwg = GX * gridDim.y;
    const int orig = blockIdx.y * GX + blockIdx.x;
    const int q8 = nwg >> 3, r8 = nwg & 7;
    const int xcd = orig & 7, cidx = orig >> 3;
    const int swz = (xcd < r8 ? xcd * (q8 + 1) : r8 * (q8 + 1) + (xcd - r8) * q8) + cidx;
    const int m0 = (swz / GX) * BM;
    const int n0 = (swz % GX) * BN;

    const int w = t >> 6;
    const int lane = t & 63;
    const int id = lane & 15;
    const int q = lane >> 4;

    floatx4 acc[SM][JR];
#pragma unroll
    for (int s = 0; s < SM; s++)
#pragma unroll
        for (int j = 0; j < JR; j++) acc[s][j] = (floatx4)0.0f;

    const int ar = t >> 2;          // 0..63
    const int ac = (t & 3) * 8;     // 0,8,16,24

    // per-thread source element bases (row fixed; col walks by k0)
    const long ea0 = (long)min(m0 + ar, M - 1) * K + ac;
    const long ea1 = (SM == 2) ? (long)min(m0 + ar + 64, M - 1) * K + ac : ea0;
    const long eb0 = (long)min(n0 + ar, N - 1) * K + ac;
    const long eb1 = (JR == 8) ? (long)min(n0 + ar + 64, N - 1) * K + ac : eb0;

    // prologue: stage tile 0 into buffer 0
    {
        ushort8 u; floatx4 f0, f1;
        ld_any(A, ea0, af32, u, f0, f1);
        *(ushort8*)(sA[0] + ar * LDT + ac) = cv_any(af32, u, f0, f1);
        if (SM == 2) {
            ld_any(A, ea1, af32, u, f0, f1);
            *(ushort8*)(sA[0] + (ar + 64) * LDT + ac) = cv_any(af32, u, f0, f1);
        }
        ld_any(Bt, eb0, bf32, u, f0, f1);
        *(ushort8*)(sB[0] + ar * LDT + ac) = cv_any(bf32, u, f0, f1);
        if (JR == 8) {
            ld_any(Bt, eb1, bf32, u, f0, f1);
            *(ushort8*)(sB[0] + (ar + 64) * LDT + ac) = cv_any(bf32, u, f0, f1);
        }
        __syncthreads();
    }

    auto STEP = [&](int k0, const unsigned short* sAr, const unsigned short* sBr,
                    unsigned short* sAw, unsigned short* sBw, bool last) {
        ushort8 na0, na1, nb0, nb1;
        floatx4 fa00, fa01, fa10, fa11, fb00, fb01, fb10, fb11;
        if (!last) {                       // issue next tile's loads FIRST
            ld_any(A, ea0 + k0 + BK, af32, na0, fa00, fa01);
            if (SM == 2) ld_any(A, ea1 + k0 + BK, af32, na1, fa10, fa11);
            ld_any(Bt, eb0 + k0 + BK, bf32, nb0, fb00, fb01);
            if (JR == 8) ld_any(Bt, eb1 + k0 + BK, bf32, nb1, fb10, fb11);
        }
        short8 afrag[SM], bfrag[JR];
#pragma unroll
        for (int s = 0; s < SM; s++)
            afrag[s] = *(const short8*)(sAr + ((SM == 2 ? 32 * w + 16 * s : 16 * w) + id) * LDT + q * 8);
#pragma unroll
        for (int j = 0; j < JR; j++)
            bfrag[j] = *(const short8*)(sBr + (16 * j + id) * LDT + q * 8);
#pragma unroll
        for (int s = 0; s < SM; s++)
#pragma unroll
            for (int j = 0; j < JR; j++)
                acc[s][j] = __builtin_amdgcn_mfma_f32_16x16x32_bf16(
                    bfrag[j], afrag[s], acc[s][j], 0, 0, 0);   // SWAPPED operands
        if (!last) {
            *(ushort8*)(sAw + ar * LDT + ac) = cv_any(af32, na0, fa00, fa01);
            if (SM == 2) *(ushort8*)(sAw + (ar + 64) * LDT + ac) = cv_any(af32, na1, fa10, fa11);
            *(ushort8*)(sBw + ar * LDT + ac) = cv_any(bf32, nb0, fb00, fb01);
            if (JR == 8) *(ushort8*)(sBw + (ar + 64) * LDT + ac) = cv_any(bf32, nb1, fb10, fb11);
            __syncthreads();               // single barrier per K-step
        }
    };

    for (int k0 = 0; k0 < K; k0 += 2 * BK) {     // K/BK always even here
        STEP(k0, sA[0], sB[0], sA[1], sB[1], false);
        STEP(k0 + BK, sA[1], sB[1], sA[0], sB[0], k0 + 2 * BK >= K);
    }

    // epilogue: swapped D layout -> lane holds row m (fixed), 4 consecutive cols
#pragma unroll
    for (int s = 0; s < SM; s++) {
        const int row = m0 + (SM == 2 ? 32 * w + 16 * s : 16 * w) + id;
        if (row < M) {
#pragma unroll
            for (int j = 0; j < JR; j++) {
                const int colb = n0 + 16 * j + 4 * q;
                floatx4 v = acc[s][j];
                if (hasb) v = v + *(const floatx4*)(bias + colb);
                const long off = coff + (long)row * N + colb;
                if (of32) {
                    *(floatx4*)((float*)Cv + off) = v;
                } else {
                    bf4 o;
#pragma unroll
                    for (int r = 0; r < 4; r++) o[r] = f2bf(v[r]);
                    *(bf4*)((unsigned short*)Cv + off) = o;
                }
                if (Cv2) {                 // dual-write (z -> d_out)
                    const long off2 = c2off + (long)row * N + colb;
                    if (isf32) {
                        *(floatx4*)((float*)Cv2 + off2) = v;
                    } else {
                        bf4 o;
#pragma unroll
                        for (int r = 0; r < 4; r++) o[r] = f2bf(v[r]);
                        *(bf4*)((unsigned short*)Cv2 + off2) = o;
                    }
                }
            }
        }
    }
}

// ------- aggregation: O[i] = dinv[i]*(sum_j T[csr_j]*dinv[csr_j] + T[i]*dinv[i]) + b
// optional dual-write of the result into d_out (fuses old k_out for h2).

template <int D>
__global__ __launch_bounds__(256) void k_agg(const unsigned short* __restrict__ T,
                                             const int* __restrict__ rs,
                                             const int* __restrict__ csr,
                                             const float* __restrict__ dinv,
                                             const float* __restrict__ bias,
                                             unsigned short* __restrict__ O,
                                             void* __restrict__ O2, long o2off,
                                             const int* __restrict__ flags, int n) {
    constexpr int TPN = D / 8;
    constexpr int NPB = 256 / TPN;
    int lt = threadIdx.x % TPN;
    int node = blockIdx.x * NPB + threadIdx.x / TPN;
    if (node >= n) return;
    int off = lt * 8;
    float acc[8];
#pragma unroll
    for (int i = 0; i < 8; i++) acc[i] = 0.0f;
    int beg = rs[node], end = rs[node + 1];
    for (int j = beg; j < end; j++) {
        int s = csr[j];
        if ((unsigned)s >= (unsigned)n) continue;
        float wgt = dinv[s];
        ushort8 v = *(const ushort8*)(T + (long)s * D + off);
#pragma unroll
        for (int i = 0; i < 8; i++) acc[i] += wgt * bf2f(v[i]);
    }
    float di = dinv[node];
    ushort8 sv = *(const ushort8*)(T + (long)node * D + off);
    float res[8];
    ushort8 o;
#pragma unroll
    for (int i = 0; i < 8; i++) {
        res[i] = di * (acc[i] + di * bf2f(sv[i])) + (bias ? bias[off + i] : 0.0f);
        o[i] = f2bf(res[i]);
    }
    *(ushort8*)(O + (long)node * D + off) = o;
    if (O2) {
        const long p = o2off + (long)node * D + off;
        if (flags[0]) {
            float* dst = (float*)O2 + p;
            floatx4 v0, v1;
#pragma unroll
            for (int i = 0; i < 4; i++) { v0[i] = res[i]; v1[i] = res[4 + i]; }
            *(floatx4*)(dst) = v0;
            *(floatx4*)(dst + 4) = v1;
        } else {
            *(ushort8*)((unsigned short*)O2 + p) = o;
        }
    }
}

// ---------------- launch ----------------

extern "C" void kernel_launch(void* const* d_in, const int* in_sizes, int n_in,
                              void* d_out, int out_size, void* d_ws, size_t ws_size,
                              hipStream_t stream) {
    const int IN  = in_sizes[7];           // 1024
    const int HID = in_sizes[3];           // 512
    const int OUT = in_sizes[5];           // 128
    const int Nn  = in_sizes[0] / IN;      // 20000
    const int E   = in_sizes[1] / 2;       // 160000

    const void* X   = d_in[0];
    const int*  ei  = (const int*)d_in[1];
    const void* W1  = d_in[2];
    const void* b1  = d_in[3];
    const void* W2  = d_in[4];
    const void* b2  = d_in[5];
    const void* b3  = d_in[6];
    const void* b4  = d_in[7];
    const void* Hd1 = d_in[8];

    char* base = (char*)d_ws;
    size_t o = 0;
    auto carve = [&](size_t bytes) -> char* {
        char* p = base + o;
        o = (o + bytes + 255) & ~(size_t)255;
        return p;
    };
    int*   flags  = (int*)carve(2 * 4);
    int*   deg    = (int*)carve((size_t)Nn * 4);
    int*   rowst  = (int*)carve((size_t)(Nn + 1) * 4);
    int*   cursor = (int*)carve((size_t)Nn * 4);
    float* dinv   = (float*)carve((size_t)Nn * 4);
    int*   csr    = (int*)carve((size_t)E * 4);
    float* biasf  = (float*)carve((size_t)(HID + OUT + HID + IN) * 4);
    float* bc1 = biasf, *bc2 = biasf + HID, *bc3 = biasf + HID + OUT,
         *bc4 = biasf + HID + OUT + HID;
    unsigned short* W1t  = (unsigned short*)carve((size_t)IN * HID * 2);
    unsigned short* W2t  = (unsigned short*)carve((size_t)HID * OUT * 2);
    unsigned short* H1t  = (unsigned short*)carve((size_t)OUT * OUT * 2);
    unsigned short* t1   = (unsigned short*)carve((size_t)Nn * HID * 2); // also g4
    unsigned short* h1   = (unsigned short*)carve((size_t)Nn * HID * 2);
    unsigned short* h3   = (unsigned short*)carve((size_t)Nn * HID * 2);
    unsigned short* t2   = (unsigned short*)carve((size_t)Nn * OUT * 2); // also g3
    unsigned short* h2ws = (unsigned short*)carve((size_t)Nn * OUT * 2);
    unsigned short* zws  = (unsigned short*)carve((size_t)Nn * OUT * 2);

    // --- detection (+deg zero) + graph setup ---
    hipMemsetAsync(flags, 0, 8, stream);
    int nPairs = 1 << 20;
    {
        int gmax = nPairs;  // covers E (160k) and Nn (20k) too
        k_detect<<<(gmax + 255) / 256, 256, 0, stream>>>(
            (const unsigned short*)X, nPairs, ei, E, Nn, flags, deg);
    }

    k_cvtb<<<(HID + OUT + HID + IN + 255) / 256, 256, 0, stream>>>(
        b1, b2, b3, b4, biasf, HID, OUT, HID, IN, flags);

    k_tcvt<<<dim3((IN + 31) / 32, (HID + 31) / 32), 256, 0, stream>>>(W1, W1t, HID, IN, flags);
    k_tcvt<<<dim3((HID + 31) / 32, (OUT + 31) / 32), 256, 0, stream>>>(W2, W2t, OUT, HID, flags);
    k_tcvt<<<dim3((OUT + 31) / 32, (OUT + 31) / 32), 256, 0, stream>>>(Hd1, H1t, OUT, OUT, flags);

    k_count<<<(E + 255) / 256, 256, 0, stream>>>(ei, E, Nn, flags, deg);
    k_dinv<<<(Nn + 255) / 256, 256, 0, stream>>>(deg, dinv, Nn);
    k_scan<<<1, 1024, 0, stream>>>(deg, rowst, cursor, Nn);
    k_fill<<<(E + 255) / 256, 256, 0, stream>>>(ei, E, Nn, flags, cursor, csr);

    dim3 blk(256);
    auto ggrid = [&](int Ncols, int bn, int bm) {
        return dim3((Ncols + bn - 1) / bn, (Nn + bm - 1) / bm);
    };
    const long h2Off = (long)Nn * OUT, h4Off = (long)Nn * OUT * 2;

    // conv1: t1 = X @ W1^T (both maybe-fp32, converted in staging) ; h1 = S*t1 + b1
    gemm_nt<128, 64><<<ggrid(HID, 64, 128), blk, 0, stream>>>(
        X, 1, W1, 1, t1, 0, nullptr, 0, nullptr, Nn, HID, IN, 0, flags);
    k_agg<512><<<(Nn * 64 + 255) / 256, blk, 0, stream>>>(
        t1, rowst, csr, dinv, bc1, h1, nullptr, 0, flags, Nn);

    // conv2: t2 = h1 @ W2^T ; h2 = S*t2 + b2 (dual-write h2 -> d_out)
    gemm_nt<64, 64><<<ggrid(OUT, 64, 64), blk, 0, stream>>>(
        h1, 0, W2, 1, t2, 0, nullptr, 0, nullptr, Nn, OUT, HID, 0, flags);
    k_agg<128><<<(Nn * 16 + 255) / 256, blk, 0, stream>>>(
        t2, rowst, csr, dinv, bc2, h2ws, d_out, h2Off, flags, Nn);

    // z = h2 @ head1 (dual-write z -> d_out)
    gemm_nt<64, 64><<<ggrid(OUT, 64, 64), blk, 0, stream>>>(
        h2ws, 0, H1t, 0, zws, 0, d_out, 0, nullptr, Nn, OUT, OUT, 0, flags);

    // conv3 (agg-first, tied W2^T): g3 = S*z ; h3 = g3 @ W2 + b3
    k_agg<128><<<(Nn * 16 + 255) / 256, blk, 0, stream>>>(
        zws, rowst, csr, dinv, nullptr, t2, nullptr, 0, flags, Nn);
    gemm_nt<128, 64><<<ggrid(HID, 64, 128), blk, 0, stream>>>(
        t2, 0, W2t, 0, h3, 0, nullptr, 0, bc3, Nn, HID, OUT, 0, flags);

    // conv4 (agg-first, tied W1^T): g4 = S*h3 ; h4 = g4 @ W1 + b4 -> d_out
    k_agg<512><<<(Nn * 64 + 255) / 256, blk, 0, stream>>>(
        h3, rowst, csr, dinv, nullptr, t1, nullptr, 0, flags, Nn);
    gemm_nt<128, 128><<<ggrid(IN, 128, 128), blk, 0, stream>>>(
        t1, 0, W1t, 0, d_out, h4Off, nullptr, 0, bc4, Nn, IN, HID, 1, flags);
}

// Round 7
// 533.478 us; speedup vs baseline: 1.1453x; 1.1453x over previous
//
#include <hip/hip_runtime.h>

typedef short   short8  __attribute__((ext_vector_type(8)));
typedef unsigned short ushort8 __attribute__((ext_vector_type(8)));
typedef unsigned short bf4     __attribute__((ext_vector_type(4)));
typedef float   floatx4 __attribute__((ext_vector_type(4)));

__device__ __forceinline__ float bf2f(unsigned short h) {
    unsigned int u = ((unsigned int)h) << 16;
    return __builtin_bit_cast(float, u);
}
__device__ __forceinline__ unsigned short f2bf(float f) {
    unsigned int u = __builtin_bit_cast(unsigned int, f);
    u += 0x7fffu + ((u >> 16) & 1u);   // round-to-nearest-even
    return (unsigned short)(u >> 16);
}

// ---------------- fused dtype detection + deg zeroing ----------------
// flags[0] != 0  =>  float tensors delivered as fp32 (else bf16)
// flags[1] != 0  =>  edge_index delivered as int32 (else int64)

__global__ __launch_bounds__(256) void k_detect(const unsigned short* __restrict__ X,
                                                int nPairs, const int* __restrict__ ei,
                                                int E, int n,
                                                int* __restrict__ flags,
                                                int* __restrict__ deg) {
    int i = blockIdx.x * 256 + threadIdx.x;
    if (i < nPairs) {
        unsigned short w = X[2 * i];
        if ((w & 0x7F80u) == 0x7F80u) atomicOr(&flags[0], 1);
    }
    if (i < E) {
        if (ei[2 * i + 1] != 0) atomicOr(&flags[1], 1);
    }
    if (i < n) deg[i] = 0;
}

// ---------------- fused bias converts (4 segments -> one fp32 buffer) --------

__global__ __launch_bounds__(256) void k_cvtb(const void* __restrict__ b1,
                                              const void* __restrict__ b2,
                                              const void* __restrict__ b3,
                                              const void* __restrict__ b4,
                                              float* __restrict__ out,
                                              int L1, int L2, int L3, int L4,
                                              const int* __restrict__ flags) {
    int i = blockIdx.x * 256 + threadIdx.x;
    int n = L1 + L2 + L3 + L4;
    if (i >= n) return;
    const void* src; int off;
    if (i < L1)                { src = b1; off = i; }
    else if (i < L1 + L2)      { src = b2; off = i - L1; }
    else if (i < L1 + L2 + L3) { src = b3; off = i - L1 - L2; }
    else                       { src = b4; off = i - L1 - L2 - L3; }
    out[i] = flags[0] ? ((const float*)src)[off]
                      : bf2f(((const unsigned short*)src)[off]);
}

// bulk convert (or passthrough-copy) to bf16, 8 elems/thread, coalesced.
// Round-6 post-mortem: in-GEMM dual-dtype staging (ld_any/cv_any) collapsed
// the register budget to 60 VGPR -> loads waited immediately -> conv1 133us.
// Pre-converting once (this kernel, ~20us total) keeps the GEMM single-dtype
// so the double-buffer prefetch schedule survives. Do NOT re-fuse.
__global__ __launch_bounds__(256) void k_cvt8(const void* __restrict__ in,
                                              unsigned short* __restrict__ out,
                                              long n8, const int* __restrict__ flags) {
    long i = (long)blockIdx.x * 256 + threadIdx.x;
    if (i >= n8) return;
    ushort8 o;
    if (flags[0]) {
        const floatx4* f = (const floatx4*)in + i * 2;
        floatx4 a = f[0], b = f[1];
#pragma unroll
        for (int j = 0; j < 4; j++) { o[j] = f2bf(a[j]); o[4 + j] = f2bf(b[j]); }
    } else {
        o = *((const ushort8*)in + i);
    }
    *((ushort8*)out + i) = o;
}

// ---------------- LDS-tiled transpose-convert: out[c][r] = bf16(in[r][c]) ----

__global__ __launch_bounds__(256) void k_tcvt(const void* __restrict__ in,
                                              unsigned short* __restrict__ out,
                                              int R, int C, const int* __restrict__ flags) {
    __shared__ unsigned short tl[32][40];
    const int c0 = blockIdx.x * 32, r0 = blockIdx.y * 32;
    const int tx = threadIdx.x & 31, ty = threadIdx.x >> 5;   // 32x8
    const bool f32 = flags[0] != 0;
#pragma unroll
    for (int k = 0; k < 32; k += 8) {
        int r = r0 + ty + k, c = c0 + tx;
        unsigned short v = 0;
        if (r < R && c < C)
            v = f32 ? f2bf(((const float*)in)[(long)r * C + c])
                    : ((const unsigned short*)in)[(long)r * C + c];
        tl[ty + k][tx] = v;
    }
    __syncthreads();
#pragma unroll
    for (int k = 0; k < 32; k += 8) {
        int c = c0 + ty + k, r = r0 + tx;
        if (c < C && r < R) out[(long)c * R + r] = tl[tx][ty + k];
    }
}

// ---------------- graph setup ----------------

__global__ __launch_bounds__(256) void k_count(const int* __restrict__ ei, int E, int n,
                                               const int* __restrict__ flags,
                                               int* __restrict__ deg) {
    int e = blockIdx.x * 256 + threadIdx.x;
    if (e >= E) return;
    int sh = (flags[1] == 0) ? 1 : 0;           // int64 -> stride-2 words
    int d = ei[(long)(E + e) << sh];
    if ((unsigned)d < (unsigned)n) atomicAdd(&deg[d], 1);
}

__global__ __launch_bounds__(256) void k_dinv(const int* __restrict__ deg,
                                              float* __restrict__ dinv, int n) {
    int i = blockIdx.x * 256 + threadIdx.x;
    if (i < n) dinv[i] = rsqrtf((float)(deg[i] + 1));  // +1 self-loop
}

__global__ __launch_bounds__(1024) void k_scan(const int* __restrict__ deg,
                                               int* __restrict__ row_start,
                                               int* __restrict__ cursor, int n) {
    __shared__ int sums[1024];
    int t = threadIdx.x;
    int CH = (n + 1 + 1023) / 1024;
    int base = t * CH;
    int s = 0;
    for (int i = 0; i < CH; i++) {
        int idx = base + i;
        if (idx < n) s += deg[idx];
    }
    sums[t] = s;
    __syncthreads();
    for (int off = 1; off < 1024; off <<= 1) {
        int v = (t >= off) ? sums[t - off] : 0;
        __syncthreads();
        if (t >= off) sums[t] += v;
        __syncthreads();
    }
    int run = (t > 0) ? sums[t - 1] : 0;
    for (int i = 0; i < CH; i++) {
        int idx = base + i;
        if (idx < n) {
            row_start[idx] = run;
            cursor[idx] = run;
            run += deg[idx];
        } else if (idx == n) {
            row_start[n] = run;
        }
    }
}

__global__ __launch_bounds__(256) void k_fill(const int* __restrict__ ei, int E, int n,
                                              const int* __restrict__ flags,
                                              int* __restrict__ cursor,
                                              int* __restrict__ csr) {
    int e = blockIdx.x * 256 + threadIdx.x;
    if (e >= E) return;
    int sh = (flags[1] == 0) ? 1 : 0;
    int s = ei[(long)e << sh];
    int d = ei[(long)(E + e) << sh];
    if ((unsigned)d >= (unsigned)n || (unsigned)s >= (unsigned)n) return;
    int p = atomicAdd(&cursor[d], 1);
    csr[p] = s;
}

// ---------------- NT GEMM: C[M,N] = A[M,K] * Bt[N,K]^T (+bias), fp32 acc ------
// A, Bt bf16 ONLY (pre-converted). Output bf16, or fp32 if finalOut&&flags[0].
// Round-5 structure (best measured): LDS double-buffer, ONE barrier per
// K-step, next-tile loads issued first in each step, swapped-operand MFMA
// (mfma(b,a,acc): D rows=m lane-fixed, 4 consecutive cols -> vector stores).
// Optional dual-write epilogue (z -> d_out) from round 6 (epilogue-only, cheap).
// NOTE (round-1): all acc/frag loops MUST be #pragma unroll'd (rule #20).
// NOTE (round-6): do NOT put dtype branches in the staging path.

template <int BM, int BN>
__global__ __launch_bounds__(256, (BN == 128 ? 3 : 4))
void gemm_nt(const unsigned short* __restrict__ A,
             const unsigned short* __restrict__ Bt,
             void* __restrict__ Cv, long coff,
             void* __restrict__ Cv2, long c2off,
             const float* __restrict__ bias,
             int M, int N, int K, int finalOut,
             const int* __restrict__ flags) {
    constexpr int BK = 32, LDT = 40;   // pad 32->40: only free 2-way conflicts
    constexpr int JR = BN / 16;        // B fragments per wave
    constexpr int SM = BM / 64;        // A subtiles per wave (1 or 2)
    __shared__ unsigned short sA[2][BM * LDT];
    __shared__ unsigned short sB[2][BN * LDT];
    const bool isf32 = flags[0] != 0;
    const bool of32 = finalOut && isf32;
    const bool hasb = bias != nullptr;
    const int t = threadIdx.x;

    // bijective XCD-aware swizzle (contiguous chunk per XCD)
    const int GX = gridDim.x;
    const int nwg = GX * gridDim.y;
    const int orig = blockIdx.y * GX + blockIdx.x;
    const int q8 = nwg >> 3, r8 = nwg & 7;
    const int xcd = orig & 7, cidx = orig >> 3;
    const int swz = (xcd < r8 ? xcd * (q8 + 1) : r8 * (q8 + 1) + (xcd - r8) * q8) + cidx;
    const int m0 = (swz / GX) * BM;
    const int n0 = (swz % GX) * BN;

    const int w = t >> 6;
    const int lane = t & 63;
    const int id = lane & 15;
    const int q = lane >> 4;

    floatx4 acc[SM][JR];
#pragma unroll
    for (int s = 0; s < SM; s++)
#pragma unroll
        for (int j = 0; j < JR; j++) acc[s][j] = (floatx4)0.0f;

    const int ar = t >> 2;          // 0..63
    const int ac = (t & 3) * 8;     // 0,8,16,24

    // per-thread source row pointers (row fixed; col walks by k0)
    const unsigned short* pa0 = A + (long)min(m0 + ar, M - 1) * K + ac;
    const unsigned short* pa1 = (SM == 2)
        ? A + (long)min(m0 + ar + 64, M - 1) * K + ac : pa0;
    const unsigned short* pb0 = Bt + (long)min(n0 + ar, N - 1) * K + ac;
    const unsigned short* pb1 = (JR == 8)
        ? Bt + (long)min(n0 + ar + 64, N - 1) * K + ac : pb0;

    // prologue: stage tile 0 into buffer 0
    {
        ushort8 va0 = *(const ushort8*)(pa0);
        ushort8 va1; if (SM == 2) va1 = *(const ushort8*)(pa1);
        ushort8 vb0 = *(const ushort8*)(pb0);
        ushort8 vb1; if (JR == 8) vb1 = *(const ushort8*)(pb1);
        *(ushort8*)(sA[0] + ar * LDT + ac) = va0;
        if (SM == 2) *(ushort8*)(sA[0] + (ar + 64) * LDT + ac) = va1;
        *(ushort8*)(sB[0] + ar * LDT + ac) = vb0;
        if (JR == 8) *(ushort8*)(sB[0] + (ar + 64) * LDT + ac) = vb1;
        __syncthreads();
    }

    auto STEP = [&](int k0, const unsigned short* sAr, const unsigned short* sBr,
                    unsigned short* sAw, unsigned short* sBw, bool last) {
        ushort8 na0, na1, nb0, nb1;
        if (!last) {                       // issue next tile's loads FIRST
            na0 = *(const ushort8*)(pa0 + k0 + BK);
            if (SM == 2) na1 = *(const ushort8*)(pa1 + k0 + BK);
            nb0 = *(const ushort8*)(pb0 + k0 + BK);
            if (JR == 8) nb1 = *(const ushort8*)(pb1 + k0 + BK);
        }
        short8 afrag[SM], bfrag[JR];
#pragma unroll
        for (int s = 0; s < SM; s++)
            afrag[s] = *(const short8*)(sAr + ((SM == 2 ? 32 * w + 16 * s : 16 * w) + id) * LDT + q * 8);
#pragma unroll
        for (int j = 0; j < JR; j++)
            bfrag[j] = *(const short8*)(sBr + (16 * j + id) * LDT + q * 8);
#pragma unroll
        for (int s = 0; s < SM; s++)
#pragma unroll
            for (int j = 0; j < JR; j++)
                acc[s][j] = __builtin_amdgcn_mfma_f32_16x16x32_bf16(
                    bfrag[j], afrag[s], acc[s][j], 0, 0, 0);   // SWAPPED operands
        if (!last) {
            *(ushort8*)(sAw + ar * LDT + ac) = na0;
            if (SM == 2) *(ushort8*)(sAw + (ar + 64) * LDT + ac) = na1;
            *(ushort8*)(sBw + ar * LDT + ac) = nb0;
            if (JR == 8) *(ushort8*)(sBw + (ar + 64) * LDT + ac) = nb1;
            __syncthreads();               // single barrier per K-step
        }
    };

    for (int k0 = 0; k0 < K; k0 += 2 * BK) {     // K/BK always even here
        STEP(k0, sA[0], sB[0], sA[1], sB[1], false);
        STEP(k0 + BK, sA[1], sB[1], sA[0], sB[0], k0 + 2 * BK >= K);
    }

    // epilogue: swapped D layout -> lane holds row m (fixed), 4 consecutive cols
#pragma unroll
    for (int s = 0; s < SM; s++) {
        const int row = m0 + (SM == 2 ? 32 * w + 16 * s : 16 * w) + id;
        if (row < M) {
#pragma unroll
            for (int j = 0; j < JR; j++) {
                const int colb = n0 + 16 * j + 4 * q;
                floatx4 v = acc[s][j];
                if (hasb) v = v + *(const floatx4*)(bias + colb);
                const long off = coff + (long)row * N + colb;
                if (of32) {
                    *(floatx4*)((float*)Cv + off) = v;
                } else {
                    bf4 o;
#pragma unroll
                    for (int r = 0; r < 4; r++) o[r] = f2bf(v[r]);
                    *(bf4*)((unsigned short*)Cv + off) = o;
                }
                if (Cv2) {                 // dual-write (z -> d_out)
                    const long off2 = c2off + (long)row * N + colb;
                    if (isf32) {
                        *(floatx4*)((float*)Cv2 + off2) = v;
                    } else {
                        bf4 o;
#pragma unroll
                        for (int r = 0; r < 4; r++) o[r] = f2bf(v[r]);
                        *(bf4*)((unsigned short*)Cv2 + off2) = o;
                    }
                }
            }
        }
    }
}

// ------- aggregation: O[i] = dinv[i]*(sum_j T[csr_j]*dinv[csr_j] + T[i]*dinv[i]) + b
// optional dual-write of the result into d_out (fuses old k_out for h2).

template <int D>
__global__ __launch_bounds__(256) void k_agg(const unsigned short* __restrict__ T,
                                             const int* __restrict__ rs,
                                             const int* __restrict__ csr,
                                             const float* __restrict__ dinv,
                                             const float* __restrict__ bias,
                                             unsigned short* __restrict__ O,
                                             void* __restrict__ O2, long o2off,
                                             const int* __restrict__ flags, int n) {
    constexpr int TPN = D / 8;
    constexpr int NPB = 256 / TPN;
    int lt = threadIdx.x % TPN;
    int node = blockIdx.x * NPB + threadIdx.x / TPN;
    if (node >= n) return;
    int off = lt * 8;
    float acc[8];
#pragma unroll
    for (int i = 0; i < 8; i++) acc[i] = 0.0f;
    int beg = rs[node], end = rs[node + 1];
    for (int j = beg; j < end; j++) {
        int s = csr[j];
        if ((unsigned)s >= (unsigned)n) continue;
        float wgt = dinv[s];
        ushort8 v = *(const ushort8*)(T + (long)s * D + off);
#pragma unroll
        for (int i = 0; i < 8; i++) acc[i] += wgt * bf2f(v[i]);
    }
    float di = dinv[node];
    ushort8 sv = *(const ushort8*)(T + (long)node * D + off);
    float res[8];
    ushort8 o;
#pragma unroll
    for (int i = 0; i < 8; i++) {
        res[i] = di * (acc[i] + di * bf2f(sv[i])) + (bias ? bias[off + i] : 0.0f);
        o[i] = f2bf(res[i]);
    }
    *(ushort8*)(O + (long)node * D + off) = o;
    if (O2) {
        const long p = o2off + (long)node * D + off;
        if (flags[0]) {
            float* dst = (float*)O2 + p;
            floatx4 v0, v1;
#pragma unroll
            for (int i = 0; i < 4; i++) { v0[i] = res[i]; v1[i] = res[4 + i]; }
            *(floatx4*)(dst) = v0;
            *(floatx4*)(dst + 4) = v1;
        } else {
            *(ushort8*)((unsigned short*)O2 + p) = o;
        }
    }
}

// ---------------- launch ----------------

extern "C" void kernel_launch(void* const* d_in, const int* in_sizes, int n_in,
                              void* d_out, int out_size, void* d_ws, size_t ws_size,
                              hipStream_t stream) {
    const int IN  = in_sizes[7];           // 1024
    const int HID = in_sizes[3];           // 512
    const int OUT = in_sizes[5];           // 128
    const int Nn  = in_sizes[0] / IN;      // 20000
    const int E   = in_sizes[1] / 2;       // 160000

    const void* X   = d_in[0];
    const int*  ei  = (const int*)d_in[1];
    const void* W1  = d_in[2];
    const void* b1  = d_in[3];
    const void* W2  = d_in[4];
    const void* b2  = d_in[5];
    const void* b3  = d_in[6];
    const void* b4  = d_in[7];
    const void* Hd1 = d_in[8];

    char* base = (char*)d_ws;
    size_t o = 0;
    auto carve = [&](size_t bytes) -> char* {
        char* p = base + o;
        o = (o + bytes + 255) & ~(size_t)255;
        return p;
    };
    int*   flags  = (int*)carve(2 * 4);
    int*   deg    = (int*)carve((size_t)Nn * 4);
    int*   rowst  = (int*)carve((size_t)(Nn + 1) * 4);
    int*   cursor = (int*)carve((size_t)Nn * 4);
    float* dinv   = (float*)carve((size_t)Nn * 4);
    int*   csr    = (int*)carve((size_t)E * 4);
    float* biasf  = (float*)carve((size_t)(HID + OUT + HID + IN) * 4);
    float* bc1 = biasf, *bc2 = biasf + HID, *bc3 = biasf + HID + OUT,
         *bc4 = biasf + HID + OUT + HID;
    unsigned short* W1t  = (unsigned short*)carve((size_t)IN * HID * 2);
    unsigned short* W2t  = (unsigned short*)carve((size_t)HID * OUT * 2);
    unsigned short* H1t  = (unsigned short*)carve((size_t)OUT * OUT * 2);
    unsigned short* W1c  = (unsigned short*)carve((size_t)HID * IN * 2);
    unsigned short* W2c  = (unsigned short*)carve((size_t)OUT * HID * 2);
    unsigned short* Xb   = (unsigned short*)carve((size_t)Nn * IN * 2);
    unsigned short* t1   = (unsigned short*)carve((size_t)Nn * HID * 2); // also g4
    unsigned short* h1   = (unsigned short*)carve((size_t)Nn * HID * 2);
    unsigned short* h3   = (unsigned short*)carve((size_t)Nn * HID * 2);
    unsigned short* t2   = (unsigned short*)carve((size_t)Nn * OUT * 2); // also g3
    unsigned short* h2ws = (unsigned short*)carve((size_t)Nn * OUT * 2);
    unsigned short* zws  = (unsigned short*)carve((size_t)Nn * OUT * 2);

    // --- detection (+deg zero) + setup ---
    hipMemsetAsync(flags, 0, 8, stream);
    int nPairs = 1 << 20;
    k_detect<<<(nPairs + 255) / 256, 256, 0, stream>>>(
        (const unsigned short*)X, nPairs, ei, E, Nn, flags, deg);

    k_cvtb<<<(HID + OUT + HID + IN + 255) / 256, 256, 0, stream>>>(
        b1, b2, b3, b4, biasf, HID, OUT, HID, IN, flags);

    k_tcvt<<<dim3((IN + 31) / 32, (HID + 31) / 32), 256, 0, stream>>>(W1, W1t, HID, IN, flags);
    k_tcvt<<<dim3((HID + 31) / 32, (OUT + 31) / 32), 256, 0, stream>>>(W2, W2t, OUT, HID, flags);
    k_tcvt<<<dim3((OUT + 31) / 32, (OUT + 31) / 32), 256, 0, stream>>>(Hd1, H1t, OUT, OUT, flags);

    // bf16 copies of X, W1, W2 for the GEMMs (pure-bf16 load path)
    {
        long n8x = (long)Nn * IN / 8;
        k_cvt8<<<(int)((n8x + 255) / 256), 256, 0, stream>>>(X, Xb, n8x, flags);
        long n8w1 = (long)HID * IN / 8;
        k_cvt8<<<(int)((n8w1 + 255) / 256), 256, 0, stream>>>(W1, W1c, n8w1, flags);
        long n8w2 = (long)OUT * HID / 8;
        k_cvt8<<<(int)((n8w2 + 255) / 256), 256, 0, stream>>>(W2, W2c, n8w2, flags);
    }

    k_count<<<(E + 255) / 256, 256, 0, stream>>>(ei, E, Nn, flags, deg);
    k_dinv<<<(Nn + 255) / 256, 256, 0, stream>>>(deg, dinv, Nn);
    k_scan<<<1, 1024, 0, stream>>>(deg, rowst, cursor, Nn);
    k_fill<<<(E + 255) / 256, 256, 0, stream>>>(ei, E, Nn, flags, cursor, csr);

    dim3 blk(256);
    auto ggrid = [&](int Ncols, int bn, int bm) {
        return dim3((Ncols + bn - 1) / bn, (Nn + bm - 1) / bm);
    };
    const long h2Off = (long)Nn * OUT, h4Off = (long)Nn * OUT * 2;

    // conv1: t1 = Xb @ W1^T ; h1 = S*t1 + b1
    gemm_nt<128, 64><<<ggrid(HID, 64, 128), blk, 0, stream>>>(
        Xb, W1c, t1, 0, nullptr, 0, nullptr, Nn, HID, IN, 0, flags);
    k_agg<512><<<(Nn * 64 + 255) / 256, blk, 0, stream>>>(
        t1, rowst, csr, dinv, bc1, h1, nullptr, 0, flags, Nn);

    // conv2: t2 = h1 @ W2^T ; h2 = S*t2 + b2 (dual-write h2 -> d_out)
    gemm_nt<64, 64><<<ggrid(OUT, 64, 64), blk, 0, stream>>>(
        h1, W2c, t2, 0, nullptr, 0, nullptr, Nn, OUT, HID, 0, flags);
    k_agg<128><<<(Nn * 16 + 255) / 256, blk, 0, stream>>>(
        t2, rowst, csr, dinv, bc2, h2ws, d_out, h2Off, flags, Nn);

    // z = h2 @ head1 (dual-write z -> d_out)
    gemm_nt<64, 64><<<ggrid(OUT, 64, 64), blk, 0, stream>>>(
        h2ws, H1t, zws, 0, d_out, 0, nullptr, Nn, OUT, OUT, 0, flags);

    // conv3 (agg-first, tied W2^T): g3 = S*z ; h3 = g3 @ W2 + b3
    k_agg<128><<<(Nn * 16 + 255) / 256, blk, 0, stream>>>(
        zws, rowst, csr, dinv, nullptr, t2, nullptr, 0, flags, Nn);
    gemm_nt<128, 64><<<ggrid(HID, 64, 128), blk, 0, stream>>>(
        t2, W2t, h3, 0, nullptr, 0, bc3, Nn, HID, OUT, 0, flags);

    // conv4 (agg-first, tied W1^T): g4 = S*h3 ; h4 = g4 @ W1 + b4 -> d_out
    k_agg<512><<<(Nn * 64 + 255) / 256, blk, 0, stream>>>(
        h3, rowst, csr, dinv, nullptr, t1, nullptr, 0, flags, Nn);
    gemm_nt<128, 128><<<ggrid(IN, 128, 128), blk, 0, stream>>>(
        t1, W1t, d_out, h4Off, nullptr, 0, bc4, Nn, IN, HID, 1, flags);
}